// Round 4
// baseline (135.809 us; speedup 1.0000x reference)
//
#include <hip/hip_runtime.h>
#include <hip/hip_bf16.h>

#define N_EXPERTS 32
#define K_SEL 4
#define IN_C 1024
#define OUT_C 1024
#define BATCH 4096
#define NTOK (BATCH * K_SEL)   // 16384

#define BM 128
#define BN 128
#define BK 64
#define MAX_TILES (N_EXPERTS + NTOK / BM)   // 160 worst case

// bf16 workspace layout (bytes)
#define WT_ELEMS (N_EXPERTS * IN_C * OUT_C)          // 33,554,432
#define XB_ELEMS (BATCH * IN_C)                      // 4,194,304
#define CTRL_OFF_BYTES ((size_t)WT_ELEMS * 2 + (size_t)XB_ELEMS * 2)

// control ints (relative to ctrl base)
#define WS_NTILES 0
#define WS_TABLE 8                          // 4 ints per tile
#define WS_ROWLIST (WS_TABLE + MAX_TILES * 4)
#define CTRL_INTS (WS_ROWLIST + NTOK)
// fallback layout additions
#define WS_COUNTS (CTRL_INTS)
#define WS_CURSOR (CTRL_INTS + 32)

typedef __attribute__((ext_vector_type(4))) float f32x4;
typedef __attribute__((ext_vector_type(8))) short bf16x8;
typedef __attribute__((ext_vector_type(8))) unsigned short u16x8;

__device__ __forceinline__ unsigned short f2bf(float f) {
    union { float f; unsigned u; } v; v.f = f;
    unsigned r = v.u + 0x7fffu + ((v.u >> 16) & 1u);   // RNE
    return (unsigned short)(r >> 16);
}

__device__ __forceinline__ void gload16(const void* g, void* l) {
    __builtin_amdgcn_global_load_lds(
        (const __attribute__((address_space(1))) unsigned int*)g,
        (__attribute__((address_space(3))) unsigned int*)l, 16, 0, 0);
}

// ---------------- fused prep: bucket (bid 0) + wconv + xconv ----------------

#define WCONV_B0 1
#define WCONV_NB 2048                       // 32 experts x 16 n-panels x 4 k-groups
#define XCONV_B0 (WCONV_B0 + WCONV_NB)      // 2049
#define XCONV_NB (XB_ELEMS / 2048)          // 2048
#define PREP_NWG (XCONV_B0 + XCONV_NB)      // 4097

__device__ __forceinline__ void wr_tile(unsigned short* tbb, int wa0, int wa1,
                                        f32x4 R0, f32x4 R1, f32x4 R2, f32x4 R3) {
    u16x8 q0, q1;
    q0[0] = f2bf(R0.x); q0[1] = f2bf(R0.y); q0[2] = f2bf(R0.z); q0[3] = f2bf(R0.w);
    q0[4] = f2bf(R1.x); q0[5] = f2bf(R1.y); q0[6] = f2bf(R1.z); q0[7] = f2bf(R1.w);
    q1[0] = f2bf(R2.x); q1[1] = f2bf(R2.y); q1[2] = f2bf(R2.z); q1[3] = f2bf(R2.w);
    q1[4] = f2bf(R3.x); q1[5] = f2bf(R3.y); q1[6] = f2bf(R3.z); q1[7] = f2bf(R3.w);
    *(u16x8*)&tbb[wa0] = q0;
    *(u16x8*)&tbb[wa1] = q1;
}

__device__ __forceinline__ void rd_store(const unsigned short* tbb, int rr, int cc0,
                                         unsigned short* dst) {
    u16x8 o0, o1;
    const int rlo = rr & 7, rhi = rr >> 3;
    #pragma unroll
    for (int j = 0; j < 8; ++j) {
        const int sw = ((rhi ^ (j & 7)) << 3) + rlo;
        o0[j] = tbb[(cc0 + j) * 64 + sw];
        o1[j] = tbb[(cc0 + 8 + j) * 64 + sw];
    }
    *(u16x8*)dst = o0;
    *(u16x8*)(dst + 8) = o1;
}

__global__ __launch_bounds__(256)
void prep_kernel(const float* __restrict__ x, const float* __restrict__ w,
                 const int* __restrict__ idx,
                 unsigned short* __restrict__ xb, unsigned short* __restrict__ wt,
                 int* __restrict__ ctrl) {
    const int bid = blockIdx.x;
    const int t = threadIdx.x;

    if (bid >= XCONV_B0) {
        // ---- x f32 -> bf16 (nontemporal read-once) ----
        int i = ((bid - XCONV_B0) * 256 + t) << 3;
        f32x4 v0 = __builtin_nontemporal_load((const f32x4*)(x + i));
        f32x4 v1 = __builtin_nontemporal_load((const f32x4*)(x + i + 4));
        u16x8 o;
        o[0] = f2bf(v0.x); o[1] = f2bf(v0.y); o[2] = f2bf(v0.z); o[3] = f2bf(v0.w);
        o[4] = f2bf(v1.x); o[5] = f2bf(v1.y); o[6] = f2bf(v1.z); o[7] = f2bf(v1.w);
        *(u16x8*)(xb + i) = o;
    } else if (bid >= WCONV_B0) {
        // ---- W[e][k][n] f32 -> Wt[e][n][k] bf16 ----
        // 4 pipelined 64x64 tiles per block, dbuf bf16 LDS, chunk-XOR swizzle.
        __shared__ unsigned short tb[2][64 * 64];
        const int b = bid - WCONV_B0;
        const int e = b >> 6;
        const int p = b & 63;
        const int nb = (p & 15) << 6;
        const int kb0 = (p >> 4) << 8;       // 4 tiles x 64 k

        // write role: r = k-row, cs = n-chunk pair
        const int r = t >> 2;
        const int cs = (t & 3) << 1;
        const int c0 = (t & 3) << 4;
        const float* srcb = w + (size_t)e * (IN_C * OUT_C) + (size_t)(kb0 + r) * OUT_C + nb + c0;
        const int wa0 = r * 64 + (((cs    ) ^ (r & 7)) << 3);
        const int wa1 = r * 64 + (((cs + 1) ^ (r & 7)) << 3);

        // read role: rr = n-row (lane), cc0 = k-chunk (wave)
        const int rr = t & 63;
        const int cc0 = (t >> 6) << 4;
        unsigned short* dstb = wt + (size_t)e * (IN_C * OUT_C) + (size_t)(nb + rr) * IN_C + kb0 + cc0;

        f32x4 a0, a1, a2, a3, b0, b1, b2, b3;
        #define LDT(kt, R0, R1, R2, R3) { \
            const float* s_ = srcb + (size_t)((kt) * 64) * OUT_C; \
            R0 = __builtin_nontemporal_load((const f32x4*)s_); \
            R1 = __builtin_nontemporal_load((const f32x4*)(s_ + 4)); \
            R2 = __builtin_nontemporal_load((const f32x4*)(s_ + 8)); \
            R3 = __builtin_nontemporal_load((const f32x4*)(s_ + 12)); }

        LDT(0, a0, a1, a2, a3);
        LDT(1, b0, b1, b2, b3);
        wr_tile(&tb[0][0], wa0, wa1, a0, a1, a2, a3);
        __syncthreads();
        // kt 0
        wr_tile(&tb[1][0], wa0, wa1, b0, b1, b2, b3);
        LDT(2, a0, a1, a2, a3);
        rd_store(&tb[0][0], rr, cc0, dstb + 0 * 64);
        __syncthreads();
        // kt 1
        wr_tile(&tb[0][0], wa0, wa1, a0, a1, a2, a3);
        LDT(3, b0, b1, b2, b3);
        rd_store(&tb[1][0], rr, cc0, dstb + 1 * 64);
        __syncthreads();
        // kt 2
        wr_tile(&tb[1][0], wa0, wa1, b0, b1, b2, b3);
        rd_store(&tb[0][0], rr, cc0, dstb + 2 * 64);
        __syncthreads();
        // kt 3
        rd_store(&tb[1][0], rr, cc0, dstb + 3 * 64);
        #undef LDT
    } else {
        // ---- bucketing: count -> scan -> table -> scatter, one block ----
        __shared__ int cnt[N_EXPERTS], base[N_EXPERTS], tbase[N_EXPERTS];
        if (t < N_EXPERTS) cnt[t] = 0;
        __syncthreads();
        #pragma unroll 4
        for (int i = 0; i < NTOK / 256; ++i) {
            int e = idx[i * 256 + t] & (N_EXPERTS - 1);
            atomicAdd(&cnt[e], 1);
        }
        __syncthreads();
        if (t == 0) {
            int off = 0, tiles = 0;
            for (int e = 0; e < N_EXPERTS; ++e) {
                base[e] = off;
                tbase[e] = tiles;
                int c = cnt[e];
                tiles += (c + BM - 1) / BM;
                off += c;
            }
            ctrl[WS_NTILES] = tiles;
        }
        __syncthreads();
        if (t < N_EXPERTS) {
            int c = cnt[t], off = base[t], tt = tbase[t];
            for (int u = 0; u < c; u += BM, ++tt) {
                ctrl[WS_TABLE + tt * 4 + 0] = t;
                ctrl[WS_TABLE + tt * 4 + 1] = off + u;
                ctrl[WS_TABLE + tt * 4 + 2] = (c - u) < BM ? (c - u) : BM;
            }
            cnt[t] = off;   // becomes scatter cursor
        }
        __syncthreads();
        #pragma unroll 4
        for (int i = 0; i < NTOK / 256; ++i) {
            int s = i * 256 + t;
            int e = idx[s] & (N_EXPERTS - 1);
            int p = atomicAdd(&cnt[e], 1);
            ctrl[WS_ROWLIST + p] = s;
        }
    }
}

// ---------------- bf16 grouped GEMM (m97 structure + src-swizzle + XCD swizzle) ----

__global__ __launch_bounds__(256, 3)
void gemm_kernel(const unsigned short* __restrict__ xb,
                 const unsigned short* __restrict__ wt,
                 const float* __restrict__ bias,
                 const int* __restrict__ ctrl,
                 float* __restrict__ out) {
    // expert-clustered XCD swizzle: XCD j owns tiles [20j, 20j+20), nb-fastest
    const int swz = ((int)blockIdx.x & 7) * ((MAX_TILES * 8) >> 3) + ((int)blockIdx.x >> 3);
    const int tileIdx = swz >> 3;
    const int ntiles = ctrl[WS_NTILES];
    if (tileIdx >= ntiles) return;
    const int e     = ctrl[WS_TABLE + tileIdx * 4 + 0];
    const int list0 = ctrl[WS_TABLE + tileIdx * 4 + 1];
    const int nrows = ctrl[WS_TABLE + tileIdx * 4 + 2];
    const int n0 = (swz & 7) * BN;

    __shared__ unsigned short As[BM][BK];   // linear; content chunk-swizzled via source perm
    __shared__ unsigned short Bs[BN][BK];   // Wt rows (n-major), same swizzle
    __shared__ int rowtok[BM];

    const int t = threadIdx.x;
    const int lane = t & 63, w = t >> 6;

    if (t < BM) {
        int r = t < nrows ? t : nrows - 1;
        rowtok[t] = ctrl[WS_ROWLIST + list0 + r];
    }
    __syncthreads();

    // staging: wave w covers rows [w*32, w*32+32), 4 insts x (8 rows x 8 chunks)
    // LDS dest linear (base + lane*16); source chunk pre-swizzled so LDS[row][c']
    // holds global chunk c = c' ^ (row&7).
    const int cg = (lane & 7) ^ (lane >> 3);
    const unsigned short* asrc[4];
    const unsigned short* bsrc[4];
    #pragma unroll
    for (int i = 0; i < 4; ++i) {
        int row = (w << 5) + (i << 3) + (lane >> 3);
        asrc[i] = xb + (size_t)(rowtok[row] >> 2) * IN_C + (cg << 3);
        bsrc[i] = wt + (size_t)e * (IN_C * OUT_C) + (size_t)(n0 + row) * IN_C + (cg << 3);
    }

    const int wr = (t >> 7) & 1;          // 2x2 wave grid, 64x64 per wave
    const int wc = (t >> 6) & 1;
    const int lrow = lane & 15, lq = lane >> 4;
    const int fo0 = ((lq) ^ (lrow & 7)) << 4;       // kk=0 byte offset in row
    const int fo1 = ((4 + lq) ^ (lrow & 7)) << 4;   // kk=1
    const char* aB = (const char*)&As[wr * 64 + lrow][0];
    const char* bB = (const char*)&Bs[wc * 64 + lrow][0];

    f32x4 acc[4][4];
    #pragma unroll
    for (int m = 0; m < 4; ++m)
        #pragma unroll
        for (int n = 0; n < 4; ++n) acc[m][n] = (f32x4)0.f;

    for (int k0 = 0; k0 < IN_C; k0 += BK) {
        __syncthreads();
        #pragma unroll
        for (int i = 0; i < 4; ++i) {
            gload16(asrc[i] + k0, &As[(w << 5) + (i << 3)][0]);
            gload16(bsrc[i] + k0, &Bs[(w << 5) + (i << 3)][0]);
        }
        __syncthreads();

        #pragma unroll
        for (int kk = 0; kk < 2; ++kk) {
            const int fo = kk ? fo1 : fo0;
            bf16x8 a[4], b[4];
            #pragma unroll
            for (int m = 0; m < 4; ++m) a[m] = *(const bf16x8*)(aB + m * 2048 + fo);
            #pragma unroll
            for (int n = 0; n < 4; ++n) b[n] = *(const bf16x8*)(bB + n * 2048 + fo);
            #pragma unroll
            for (int m = 0; m < 4; ++m)
                #pragma unroll
                for (int n = 0; n < 4; ++n)
                    acc[m][n] = __builtin_amdgcn_mfma_f32_16x16x32_bf16(a[m], b[n], acc[m][n], 0, 0, 0);
        }
    }

    // C/D layout: col = lane&15, row = (lane>>4)*4 + j   [verified m89/m91]
    #pragma unroll
    for (int m = 0; m < 4; ++m) {
        #pragma unroll
        for (int j = 0; j < 4; ++j) {
            int row = wr * 64 + m * 16 + lq * 4 + j;
            if (row < nrows) {
                int s = rowtok[row];
                float* orow = out + (size_t)s * OUT_C;
                #pragma unroll
                for (int n = 0; n < 4; ++n) {
                    int col = n0 + wc * 64 + n * 16 + lrow;
                    float vv = acc[m][n][j] + bias[e * OUT_C + col];
                    vv = vv > 0.f ? vv : 0.f;
                    __builtin_nontemporal_store(vv, &orow[col]);
                }
            }
        }
    }
}

// ---------------- fallback f32 path (round-1 proven) for small ws ----------------

__global__ void count_kernel(const int* __restrict__ idx, int* __restrict__ ctrl) {
    int s = blockIdx.x * blockDim.x + threadIdx.x;
    if (s < NTOK) atomicAdd(&ctrl[WS_COUNTS + (idx[s] & (N_EXPERTS - 1))], 1);
}

__global__ void scan_kernel(int* __restrict__ ctrl) {
    if (threadIdx.x != 0) return;
    int off = 0, tiles = 0;
    for (int e = 0; e < N_EXPERTS; ++e) {
        int c = ctrl[WS_COUNTS + e];
        ctrl[WS_CURSOR + e] = off;
        for (int t = 0; t < c; t += BM) {
            ctrl[WS_TABLE + tiles * 4 + 0] = e;
            ctrl[WS_TABLE + tiles * 4 + 1] = off + t;
            ctrl[WS_TABLE + tiles * 4 + 2] = (c - t) < BM ? (c - t) : BM;
            ++tiles;
        }
        off += c;
    }
    ctrl[WS_NTILES] = tiles;
}

__global__ void scatter_kernel(const int* __restrict__ idx, int* __restrict__ ctrl) {
    int s = blockIdx.x * blockDim.x + threadIdx.x;
    if (s < NTOK) {
        int e = idx[s] & (N_EXPERTS - 1);
        int p = atomicAdd(&ctrl[WS_CURSOR + e], 1);
        ctrl[WS_ROWLIST + p] = s;
    }
}

__global__ __launch_bounds__(256, 2)
void gemm_f32_kernel(const float* __restrict__ x, const float* __restrict__ w,
                     const float* __restrict__ bias, const int* __restrict__ ctrl,
                     float* __restrict__ out) {
    int ntiles = ctrl[WS_NTILES];
    if ((int)blockIdx.x >= ntiles) return;
    const int e     = ctrl[WS_TABLE + blockIdx.x * 4 + 0];
    const int list0 = ctrl[WS_TABLE + blockIdx.x * 4 + 1];
    const int nrows = ctrl[WS_TABLE + blockIdx.x * 4 + 2];
    const int n0 = blockIdx.y * BN;

    __shared__ unsigned short As2[BM][40];
    __shared__ unsigned short Bs2[BN][40];
    __shared__ int rowtok[BM];

    const int t = threadIdx.x;
    if (t < BM) {
        int r = t < nrows ? t : nrows - 1;
        rowtok[t] = ctrl[WS_ROWLIST + list0 + r];
    }
    __syncthreads();

    const int arow = t >> 1, acol0 = (t & 1) * 16;
    const int brow = t >> 3, bcol0 = (t & 7) * 16;
    const float* xbase = x + (size_t)(rowtok[arow] >> 2) * IN_C + acol0;
    const float* wbase = w + (size_t)e * IN_C * OUT_C + (size_t)brow * OUT_C + n0 + bcol0;

    const int lane = t & 63, wid = t >> 6;
    const int wr = wid >> 1, wc = wid & 1;
    const int lrow = lane & 15, lq = lane >> 4;

    f32x4 acc[4][4];
    #pragma unroll
    for (int m = 0; m < 4; ++m)
        #pragma unroll
        for (int n = 0; n < 4; ++n) acc[m][n] = (f32x4)0.f;

    for (int k0 = 0; k0 < IN_C; k0 += 32) {
        __syncthreads();
        #pragma unroll
        for (int u = 0; u < 4; ++u) {
            f32x4 v = *(const f32x4*)(xbase + k0 + 4 * u);
            ushort4 pk;
            pk.x = f2bf(v.x); pk.y = f2bf(v.y); pk.z = f2bf(v.z); pk.w = f2bf(v.w);
            *(ushort4*)&As2[arow][acol0 + 4 * u] = pk;
        }
        #pragma unroll
        for (int u = 0; u < 4; ++u) {
            f32x4 v = *(const f32x4*)(wbase + (size_t)k0 * OUT_C + 4 * u);
            Bs2[bcol0 + 4 * u + 0][brow] = f2bf(v.x);
            Bs2[bcol0 + 4 * u + 1][brow] = f2bf(v.y);
            Bs2[bcol0 + 4 * u + 2][brow] = f2bf(v.z);
            Bs2[bcol0 + 4 * u + 3][brow] = f2bf(v.w);
        }
        __syncthreads();

        bf16x8 a[4], b[4];
        #pragma unroll
        for (int m = 0; m < 4; ++m) a[m] = *(const bf16x8*)&As2[wr * 64 + m * 16 + lrow][lq * 8];
        #pragma unroll
        for (int n = 0; n < 4; ++n) b[n] = *(const bf16x8*)&Bs2[wc * 64 + n * 16 + lrow][lq * 8];
        #pragma unroll
        for (int m = 0; m < 4; ++m)
            #pragma unroll
            for (int n = 0; n < 4; ++n)
                acc[m][n] = __builtin_amdgcn_mfma_f32_16x16x32_bf16(a[m], b[n], acc[m][n], 0, 0, 0);
    }

    #pragma unroll
    for (int m = 0; m < 4; ++m) {
        #pragma unroll
        for (int j = 0; j < 4; ++j) {
            int row = wr * 64 + m * 16 + lq * 4 + j;
            if (row < nrows) {
                int s = rowtok[row];
                float* orow = out + (size_t)s * OUT_C;
                #pragma unroll
                for (int n = 0; n < 4; ++n) {
                    int col = n0 + wc * 64 + n * 16 + lrow;
                    float vv = acc[m][n][j] + bias[e * OUT_C + col];
                    orow[col] = vv > 0.f ? vv : 0.f;
                }
            }
        }
    }
}

// ---------------- launch ----------------

extern "C" void kernel_launch(void* const* d_in, const int* in_sizes, int n_in,
                              void* d_out, int out_size, void* d_ws, size_t ws_size,
                              hipStream_t stream) {
    const float* x    = (const float*)d_in[0];
    const int*   idx  = (const int*)d_in[1];
    const float* w    = (const float*)d_in[2];
    const float* bias = (const float*)d_in[3];
    float* out = (float*)d_out;

    const size_t need = CTRL_OFF_BYTES + (size_t)(CTRL_INTS + 64) * sizeof(int);
    if (ws_size >= need) {
        unsigned short* wt = (unsigned short*)d_ws;
        unsigned short* xb = (unsigned short*)((char*)d_ws + (size_t)WT_ELEMS * 2);
        int* ctrl = (int*)((char*)d_ws + CTRL_OFF_BYTES);

        prep_kernel<<<PREP_NWG, 256, 0, stream>>>(x, w, idx, xb, wt, ctrl);
        gemm_kernel<<<MAX_TILES * 8, 256, 0, stream>>>(xb, wt, bias, ctrl, out);
    } else {
        int* ctrl = (int*)d_ws;
        hipMemsetAsync(ctrl, 0, (CTRL_INTS + 64) * sizeof(int), stream);
        count_kernel<<<NTOK / 256, 256, 0, stream>>>(idx, ctrl);
        scan_kernel<<<1, 64, 0, stream>>>(ctrl);
        scatter_kernel<<<NTOK / 256, 256, 0, stream>>>(idx, ctrl);
        dim3 grid(MAX_TILES, OUT_C / BN);
        gemm_f32_kernel<<<grid, 256, 0, stream>>>(x, w, bias, ctrl, out);
    }
}

// Round 5
// 130.190 us; speedup vs baseline: 1.0432x; 1.0432x over previous
//
#include <hip/hip_runtime.h>
#include <hip/hip_bf16.h>

#define N_EXPERTS 32
#define K_SEL 4
#define IN_C 1024
#define OUT_C 1024
#define BATCH 4096
#define NTOK (BATCH * K_SEL)   // 16384

#define BM 128
#define BN 128
#define BK 64
#define MAX_TILES (N_EXPERTS + NTOK / BM)   // 160 worst case

// bf16 workspace layout (bytes)
#define WT_ELEMS (N_EXPERTS * IN_C * OUT_C)          // 33,554,432
#define XB_ELEMS (BATCH * IN_C)                      // 4,194,304
#define CTRL_OFF_BYTES ((size_t)WT_ELEMS * 2 + (size_t)XB_ELEMS * 2)

// control ints (relative to ctrl base)
#define WS_NTILES 0
#define WS_TABLE 8                          // 4 ints per tile
#define WS_ROWLIST (WS_TABLE + MAX_TILES * 4)
#define CTRL_INTS (WS_ROWLIST + NTOK)
// fallback layout additions
#define WS_COUNTS (CTRL_INTS)
#define WS_CURSOR (CTRL_INTS + 32)

typedef __attribute__((ext_vector_type(4))) float f32x4;
typedef __attribute__((ext_vector_type(8))) short bf16x8;
typedef __attribute__((ext_vector_type(8))) unsigned short u16x8;

__device__ __forceinline__ unsigned short f2bf(float f) {
    union { float f; unsigned u; } v; v.f = f;
    unsigned r = v.u + 0x7fffu + ((v.u >> 16) & 1u);   // RNE
    return (unsigned short)(r >> 16);
}

__device__ __forceinline__ void gload16(const void* g, void* l) {
    __builtin_amdgcn_global_load_lds(
        (const __attribute__((address_space(1))) unsigned int*)g,
        (__attribute__((address_space(3))) unsigned int*)l, 16, 0, 0);
}

// ---------------- fused prep: bucket (bid 0) + wconv-blocked + xconv ----------------
// wtb layout: [e][np 8][kp 16][row 128][chunk_phys 8][8 elems], where the data at
// (row, chunk_phys) is global k-chunk chunk_log = chunk_phys ^ (row&7) of
// n = np*128+row. This makes GEMM B-staging fully linear (1KB per instruction).

#define WCONV_B0 1
#define WCONV_NB (N_EXPERTS * 64)           // 2048: block = (e, 16 k-rows)
#define XCONV_B0 (WCONV_B0 + WCONV_NB)      // 2049
#define XCONV_NB (XB_ELEMS / 2048)          // 2048
#define PREP_NWG (XCONV_B0 + XCONV_NB)      // 4097

__global__ __launch_bounds__(256)
void prep_kernel(const float* __restrict__ x, const float* __restrict__ w,
                 const int* __restrict__ idx,
                 unsigned short* __restrict__ xb, unsigned short* __restrict__ wt,
                 int* __restrict__ ctrl) {
    const int bid = blockIdx.x;
    const int t = threadIdx.x;

    if (bid >= XCONV_B0) {
        // ---- x f32 -> bf16 ----
        int i = ((bid - XCONV_B0) * 256 + t) << 3;
        f32x4 v0 = *(const f32x4*)(x + i);
        f32x4 v1 = *(const f32x4*)(x + i + 4);
        u16x8 o;
        o[0] = f2bf(v0.x); o[1] = f2bf(v0.y); o[2] = f2bf(v0.z); o[3] = f2bf(v0.w);
        o[4] = f2bf(v1.x); o[5] = f2bf(v1.y); o[6] = f2bf(v1.z); o[7] = f2bf(v1.w);
        *(u16x8*)(xb + i) = o;
    } else if (bid >= WCONV_B0) {
        // ---- W[e][k][n] f32 -> blocked wtb, 16 k-rows per block ----
        __shared__ unsigned short tbuf[16 * 1024];   // 32 KB, [k_local][n]
        const int b = bid - WCONV_B0;
        const int e = b >> 6;
        const int sub = b & 63;                      // 64 k-groups of 16 rows
        const int kb0 = sub << 4;
        const float* src = w + ((size_t)e << 20) + ((size_t)kb0 << 10) + (t << 2);

        // phase 1: fully-linear read of 64KB (16 rows x 4KB), convert, LDS store
        f32x4 ra[8], rb[8];
        #pragma unroll
        for (int j = 0; j < 8; ++j) ra[j] = *(const f32x4*)(src + (j << 10));
        #pragma unroll
        for (int j = 0; j < 8; ++j) rb[j] = *(const f32x4*)(src + ((8 + j) << 10));
        #pragma unroll
        for (int j = 0; j < 8; ++j) {
            ushort4 pk;
            pk.x = f2bf(ra[j].x); pk.y = f2bf(ra[j].y);
            pk.z = f2bf(ra[j].z); pk.w = f2bf(ra[j].w);
            *(ushort4*)&tbuf[(j << 10) + (t << 2)] = pk;
        }
        #pragma unroll
        for (int j = 0; j < 8; ++j) {
            ushort4 pk;
            pk.x = f2bf(rb[j].x); pk.y = f2bf(rb[j].y);
            pk.z = f2bf(rb[j].z); pk.w = f2bf(rb[j].w);
            *(ushort4*)&tbuf[((8 + j) << 10) + (t << 2)] = pk;
        }
        __syncthreads();

        // phase 2: per thread one (row, cl) pair, 8 np tiles
        const int row = t & 127, cl = t >> 7;        // cl in {0,1}
        const int kp = sub >> 2, q = sub & 3;        // tile k-phase, quarter
        const int chunk = (q << 1) + cl;             // chunk_log in tile
        const int phys = chunk ^ (row & 7);
        #pragma unroll
        for (int np = 0; np < 8; ++np) {
            const int n = (np << 7) + row;
            u16x8 o;
            #pragma unroll
            for (int j = 0; j < 8; ++j)
                o[j] = tbuf[(((cl << 3) + j) << 10) + n];
            unsigned short* dst = wt
                + ((((size_t)e * 8 + np) * 16 + kp) << 13)
                + (row << 6) + (phys << 3);
            *(u16x8*)dst = o;
        }
    } else {
        // ---- bucketing: count -> scan -> table -> scatter, one block ----
        __shared__ int cnt[N_EXPERTS], base[N_EXPERTS], tbase[N_EXPERTS];
        if (t < N_EXPERTS) cnt[t] = 0;
        __syncthreads();
        #pragma unroll 4
        for (int i = 0; i < NTOK / 256; ++i) {
            int e = idx[i * 256 + t] & (N_EXPERTS - 1);
            atomicAdd(&cnt[e], 1);
        }
        __syncthreads();
        if (t == 0) {
            int off = 0, tiles = 0;
            for (int e = 0; e < N_EXPERTS; ++e) {
                base[e] = off;
                tbase[e] = tiles;
                int c = cnt[e];
                tiles += (c + BM - 1) / BM;
                off += c;
            }
            ctrl[WS_NTILES] = tiles;
        }
        __syncthreads();
        if (t < N_EXPERTS) {
            int c = cnt[t], off = base[t], tt = tbase[t];
            for (int u = 0; u < c; u += BM, ++tt) {
                ctrl[WS_TABLE + tt * 4 + 0] = t;
                ctrl[WS_TABLE + tt * 4 + 1] = off + u;
                ctrl[WS_TABLE + tt * 4 + 2] = (c - u) < BM ? (c - u) : BM;
            }
            cnt[t] = off;   // becomes scatter cursor
        }
        __syncthreads();
        #pragma unroll 4
        for (int i = 0; i < NTOK / 256; ++i) {
            int s = i * 256 + t;
            int e = idx[s] & (N_EXPERTS - 1);
            int p = atomicAdd(&cnt[e], 1);
            ctrl[WS_ROWLIST + p] = s;
        }
    }
}

// ---------------- bf16 grouped GEMM (m97 structure + blocked-linear B) ----------------

__global__ __launch_bounds__(256, 3)
void gemm_kernel(const unsigned short* __restrict__ xb,
                 const unsigned short* __restrict__ wt,
                 const float* __restrict__ bias,
                 const int* __restrict__ ctrl,
                 float* __restrict__ out) {
    // expert-clustered XCD swizzle: XCD j owns tiles [20j, 20j+20), nb-fastest
    const int swz = ((int)blockIdx.x & 7) * ((MAX_TILES * 8) >> 3) + ((int)blockIdx.x >> 3);
    const int tileIdx = swz >> 3;
    const int ntiles = ctrl[WS_NTILES];
    if (tileIdx >= ntiles) return;
    const int e     = ctrl[WS_TABLE + tileIdx * 4 + 0];
    const int list0 = ctrl[WS_TABLE + tileIdx * 4 + 1];
    const int nrows = ctrl[WS_TABLE + tileIdx * 4 + 2];
    const int np = swz & 7;
    const int n0 = np * BN;

    __shared__ unsigned short As[BM][BK];   // linear; content chunk-swizzled via source perm
    __shared__ unsigned short Bs[BN][BK];   // blocked wtb tile, copied verbatim
    __shared__ int rowtok[BM];

    const int t = threadIdx.x;
    const int lane = t & 63, w = t >> 6;

    if (t < BM) {
        int r = t < nrows ? t : nrows - 1;
        rowtok[t] = ctrl[WS_ROWLIST + list0 + r];
    }
    __syncthreads();

    // A staging: per-lane gathered rows, source chunk pre-swizzled (cg)
    const int cg = (lane & 7) ^ (lane >> 3);
    const unsigned short* asrc[4];
    #pragma unroll
    for (int i = 0; i < 4; ++i) {
        int row = (w << 5) + (i << 3) + (lane >> 3);
        asrc[i] = xb + (size_t)(rowtok[row] >> 2) * IN_C + (cg << 3);
    }
    // B staging: fully linear from blocked wtb (1KB per instruction)
    const unsigned short* bsrc[4];
    #pragma unroll
    for (int i = 0; i < 4; ++i)
        bsrc[i] = wt + (((size_t)e * 8 + np) << 17) + (w << 11) + (i << 9) + (lane << 3);

    const int wr = (t >> 7) & 1;          // 2x2 wave grid, 64x64 per wave
    const int wc = (t >> 6) & 1;
    const int lrow = lane & 15, lq = lane >> 4;
    const int fo0 = ((lq) ^ (lrow & 7)) << 4;       // kk=0 byte offset in row
    const int fo1 = ((4 + lq) ^ (lrow & 7)) << 4;   // kk=1
    const char* aB = (const char*)&As[wr * 64 + lrow][0];
    const char* bB = (const char*)&Bs[wc * 64 + lrow][0];

    f32x4 acc[4][4];
    #pragma unroll
    for (int m = 0; m < 4; ++m)
        #pragma unroll
        for (int n = 0; n < 4; ++n) acc[m][n] = (f32x4)0.f;

    for (int k0 = 0; k0 < IN_C; k0 += BK) {
        __syncthreads();
        #pragma unroll
        for (int i = 0; i < 4; ++i) {
            gload16(asrc[i] + k0, &As[(w << 5) + (i << 3)][0]);
            gload16(bsrc[i] + (k0 << 7), &Bs[(w << 5) + (i << 3)][0]);
        }
        __syncthreads();

        #pragma unroll
        for (int kk = 0; kk < 2; ++kk) {
            const int fo = kk ? fo1 : fo0;
            bf16x8 a[4], b[4];
            #pragma unroll
            for (int m = 0; m < 4; ++m) a[m] = *(const bf16x8*)(aB + m * 2048 + fo);
            #pragma unroll
            for (int n = 0; n < 4; ++n) b[n] = *(const bf16x8*)(bB + n * 2048 + fo);
            #pragma unroll
            for (int m = 0; m < 4; ++m)
                #pragma unroll
                for (int n = 0; n < 4; ++n)
                    acc[m][n] = __builtin_amdgcn_mfma_f32_16x16x32_bf16(a[m], b[n], acc[m][n], 0, 0, 0);
        }
    }

    // C/D layout: col = lane&15, row = (lane>>4)*4 + j   [verified m89/m91]
    #pragma unroll
    for (int m = 0; m < 4; ++m) {
        #pragma unroll
        for (int j = 0; j < 4; ++j) {
            int row = wr * 64 + m * 16 + lq * 4 + j;
            if (row < nrows) {
                int s = rowtok[row];
                float* orow = out + (size_t)s * OUT_C;
                #pragma unroll
                for (int n = 0; n < 4; ++n) {
                    int col = n0 + wc * 64 + n * 16 + lrow;
                    float vv = acc[m][n][j] + bias[e * OUT_C + col];
                    orow[col] = vv > 0.f ? vv : 0.f;
                }
            }
        }
    }
}

// ---------------- fallback f32 path (round-1 proven) for small ws ----------------

__global__ void count_kernel(const int* __restrict__ idx, int* __restrict__ ctrl) {
    int s = blockIdx.x * blockDim.x + threadIdx.x;
    if (s < NTOK) atomicAdd(&ctrl[WS_COUNTS + (idx[s] & (N_EXPERTS - 1))], 1);
}

__global__ void scan_kernel(int* __restrict__ ctrl) {
    if (threadIdx.x != 0) return;
    int off = 0, tiles = 0;
    for (int e = 0; e < N_EXPERTS; ++e) {
        int c = ctrl[WS_COUNTS + e];
        ctrl[WS_CURSOR + e] = off;
        for (int t = 0; t < c; t += BM) {
            ctrl[WS_TABLE + tiles * 4 + 0] = e;
            ctrl[WS_TABLE + tiles * 4 + 1] = off + t;
            ctrl[WS_TABLE + tiles * 4 + 2] = (c - t) < BM ? (c - t) : BM;
            ++tiles;
        }
        off += c;
    }
    ctrl[WS_NTILES] = tiles;
}

__global__ void scatter_kernel(const int* __restrict__ idx, int* __restrict__ ctrl) {
    int s = blockIdx.x * blockDim.x + threadIdx.x;
    if (s < NTOK) {
        int e = idx[s] & (N_EXPERTS - 1);
        int p = atomicAdd(&ctrl[WS_CURSOR + e], 1);
        ctrl[WS_ROWLIST + p] = s;
    }
}

__global__ __launch_bounds__(256, 2)
void gemm_f32_kernel(const float* __restrict__ x, const float* __restrict__ w,
                     const float* __restrict__ bias, const int* __restrict__ ctrl,
                     float* __restrict__ out) {
    int ntiles = ctrl[WS_NTILES];
    if ((int)blockIdx.x >= ntiles) return;
    const int e     = ctrl[WS_TABLE + blockIdx.x * 4 + 0];
    const int list0 = ctrl[WS_TABLE + blockIdx.x * 4 + 1];
    const int nrows = ctrl[WS_TABLE + blockIdx.x * 4 + 2];
    const int n0 = blockIdx.y * BN;

    __shared__ unsigned short As2[BM][40];
    __shared__ unsigned short Bs2[BN][40];
    __shared__ int rowtok[BM];

    const int t = threadIdx.x;
    if (t < BM) {
        int r = t < nrows ? t : nrows - 1;
        rowtok[t] = ctrl[WS_ROWLIST + list0 + r];
    }
    __syncthreads();

    const int arow = t >> 1, acol0 = (t & 1) * 16;
    const int brow = t >> 3, bcol0 = (t & 7) * 16;
    const float* xbase = x + (size_t)(rowtok[arow] >> 2) * IN_C + acol0;
    const float* wbase = w + (size_t)e * IN_C * OUT_C + (size_t)brow * OUT_C + n0 + bcol0;

    const int lane = t & 63, wid = t >> 6;
    const int wr = wid >> 1, wc = wid & 1;
    const int lrow = lane & 15, lq = lane >> 4;

    f32x4 acc[4][4];
    #pragma unroll
    for (int m = 0; m < 4; ++m)
        #pragma unroll
        for (int n = 0; n < 4; ++n) acc[m][n] = (f32x4)0.f;

    for (int k0 = 0; k0 < IN_C; k0 += 32) {
        __syncthreads();
        #pragma unroll
        for (int u = 0; u < 4; ++u) {
            f32x4 v = *(const f32x4*)(xbase + k0 + 4 * u);
            ushort4 pk;
            pk.x = f2bf(v.x); pk.y = f2bf(v.y); pk.z = f2bf(v.z); pk.w = f2bf(v.w);
            *(ushort4*)&As2[arow][acol0 + 4 * u] = pk;
        }
        #pragma unroll
        for (int u = 0; u < 4; ++u) {
            f32x4 v = *(const f32x4*)(wbase + (size_t)k0 * OUT_C + 4 * u);
            Bs2[bcol0 + 4 * u + 0][brow] = f2bf(v.x);
            Bs2[bcol0 + 4 * u + 1][brow] = f2bf(v.y);
            Bs2[bcol0 + 4 * u + 2][brow] = f2bf(v.z);
            Bs2[bcol0 + 4 * u + 3][brow] = f2bf(v.w);
        }
        __syncthreads();

        bf16x8 a[4], b[4];
        #pragma unroll
        for (int m = 0; m < 4; ++m) a[m] = *(const bf16x8*)&As2[wr * 64 + m * 16 + lrow][lq * 8];
        #pragma unroll
        for (int n = 0; n < 4; ++n) b[n] = *(const bf16x8*)&Bs2[wc * 64 + n * 16 + lrow][lq * 8];
        #pragma unroll
        for (int m = 0; m < 4; ++m)
            #pragma unroll
            for (int n = 0; n < 4; ++n)
                acc[m][n] = __builtin_amdgcn_mfma_f32_16x16x32_bf16(a[m], b[n], acc[m][n], 0, 0, 0);
    }

    #pragma unroll
    for (int m = 0; m < 4; ++m) {
        #pragma unroll
        for (int j = 0; j < 4; ++j) {
            int row = wr * 64 + m * 16 + lq * 4 + j;
            if (row < nrows) {
                int s = rowtok[row];
                float* orow = out + (size_t)s * OUT_C;
                #pragma unroll
                for (int n = 0; n < 4; ++n) {
                    int col = n0 + wc * 64 + n * 16 + lrow;
                    float vv = acc[m][n][j] + bias[e * OUT_C + col];
                    orow[col] = vv > 0.f ? vv : 0.f;
                }
            }
        }
    }
}

// ---------------- launch ----------------

extern "C" void kernel_launch(void* const* d_in, const int* in_sizes, int n_in,
                              void* d_out, int out_size, void* d_ws, size_t ws_size,
                              hipStream_t stream) {
    const float* x    = (const float*)d_in[0];
    const int*   idx  = (const int*)d_in[1];
    const float* w    = (const float*)d_in[2];
    const float* bias = (const float*)d_in[3];
    float* out = (float*)d_out;

    const size_t need = CTRL_OFF_BYTES + (size_t)(CTRL_INTS + 64) * sizeof(int);
    if (ws_size >= need) {
        unsigned short* wt = (unsigned short*)d_ws;
        unsigned short* xb = (unsigned short*)((char*)d_ws + (size_t)WT_ELEMS * 2);
        int* ctrl = (int*)((char*)d_ws + CTRL_OFF_BYTES);

        prep_kernel<<<PREP_NWG, 256, 0, stream>>>(x, w, idx, xb, wt, ctrl);
        gemm_kernel<<<MAX_TILES * 8, 256, 0, stream>>>(xb, wt, bias, ctrl, out);
    } else {
        int* ctrl = (int*)d_ws;
        hipMemsetAsync(ctrl, 0, (CTRL_INTS + 64) * sizeof(int), stream);
        count_kernel<<<NTOK / 256, 256, 0, stream>>>(idx, ctrl);
        scan_kernel<<<1, 64, 0, stream>>>(ctrl);
        scatter_kernel<<<NTOK / 256, 256, 0, stream>>>(idx, ctrl);
        dim3 grid(MAX_TILES, OUT_C / BN);
        gemm_f32_kernel<<<grid, 256, 0, stream>>>(x, w, bias, ctrl, out);
    }
}

// Round 6
// 105.326 us; speedup vs baseline: 1.2894x; 1.2361x over previous
//
#include <hip/hip_runtime.h>
#include <hip/hip_bf16.h>

#define N_EXPERTS 32
#define K_SEL 4
#define IN_C 1024
#define OUT_C 1024
#define BATCH 4096
#define NTOK (BATCH * K_SEL)   // 16384

#define BM 128
#define BN 128
#define BK 64
#define MAX_TILES (N_EXPERTS + NTOK / BM)   // 160 worst case

// workspace layout: xb (bf16) then ctrl ints
#define XB_ELEMS (BATCH * IN_C)                      // 4,194,304
#define CTRL_OFF_BYTES ((size_t)XB_ELEMS * 2)

#define WS_NTILES 0
#define WS_TABLE 8                          // 4 ints per tile
#define WS_ROWLIST (WS_TABLE + MAX_TILES * 4)
#define CTRL_INTS (WS_ROWLIST + NTOK)
// fallback layout additions
#define WS_COUNTS (CTRL_INTS)
#define WS_CURSOR (CTRL_INTS + 32)

typedef __attribute__((ext_vector_type(4))) float f32x4;
typedef __attribute__((ext_vector_type(8))) short bf16x8;
typedef __attribute__((ext_vector_type(8))) unsigned short u16x8;

__device__ __forceinline__ unsigned short f2bf(float f) {
    union { float f; unsigned u; } v; v.f = f;
    unsigned r = v.u + 0x7fffu + ((v.u >> 16) & 1u);   // RNE
    return (unsigned short)(r >> 16);
}

__device__ __forceinline__ void gload16(const void* g, void* l) {
    __builtin_amdgcn_global_load_lds(
        (const __attribute__((address_space(1))) unsigned int*)g,
        (__attribute__((address_space(3))) unsigned int*)l, 16, 0, 0);
}

// ---------------- prep: bucket (bid 0) + xconv ----------------

#define XCONV_B0 1
#define XCONV_NB (XB_ELEMS / 2048)          // 2048
#define PREP_NWG (XCONV_B0 + XCONV_NB)      // 2049

__global__ __launch_bounds__(256)
void prep_kernel(const float* __restrict__ x, const int* __restrict__ idx,
                 unsigned short* __restrict__ xb, int* __restrict__ ctrl) {
    const int bid = blockIdx.x;
    const int t = threadIdx.x;

    if (bid >= XCONV_B0) {
        // ---- x f32 -> bf16 ----
        int i = ((bid - XCONV_B0) * 256 + t) << 3;
        f32x4 v0 = *(const f32x4*)(x + i);
        f32x4 v1 = *(const f32x4*)(x + i + 4);
        u16x8 o;
        o[0] = f2bf(v0[0]); o[1] = f2bf(v0[1]); o[2] = f2bf(v0[2]); o[3] = f2bf(v0[3]);
        o[4] = f2bf(v1[0]); o[5] = f2bf(v1[1]); o[6] = f2bf(v1[2]); o[7] = f2bf(v1[3]);
        *(u16x8*)(xb + i) = o;
    } else {
        // ---- bucketing: count -> scan -> table -> scatter, one block ----
        __shared__ int cnt[N_EXPERTS], base[N_EXPERTS], tbase[N_EXPERTS];
        if (t < N_EXPERTS) cnt[t] = 0;
        __syncthreads();
        #pragma unroll 4
        for (int i = 0; i < NTOK / 256; ++i) {
            int e = idx[i * 256 + t] & (N_EXPERTS - 1);
            atomicAdd(&cnt[e], 1);
        }
        __syncthreads();
        if (t == 0) {
            int off = 0, tiles = 0;
            for (int e = 0; e < N_EXPERTS; ++e) {
                base[e] = off;
                tbase[e] = tiles;
                int c = cnt[e];
                tiles += (c + BM - 1) / BM;
                off += c;
            }
            ctrl[WS_NTILES] = tiles;
        }
        __syncthreads();
        if (t < N_EXPERTS) {
            int c = cnt[t], off = base[t], tt = tbase[t];
            for (int u = 0; u < c; u += BM, ++tt) {
                ctrl[WS_TABLE + tt * 4 + 0] = t;
                ctrl[WS_TABLE + tt * 4 + 1] = off + u;
                ctrl[WS_TABLE + tt * 4 + 2] = (c - u) < BM ? (c - u) : BM;
            }
            cnt[t] = off;   // becomes scatter cursor
        }
        __syncthreads();
        #pragma unroll 4
        for (int i = 0; i < NTOK / 256; ++i) {
            int s = i * 256 + t;
            int e = idx[s] & (N_EXPERTS - 1);
            int p = atomicAdd(&cnt[e], 1);
            ctrl[WS_ROWLIST + p] = s;
        }
    }
}

// -------- fused bf16 grouped GEMM: W f32 read + in-kernel transpose/convert --------

__global__ __launch_bounds__(256, 3)
void gemm_kernel(const unsigned short* __restrict__ xb,
                 const float* __restrict__ w,
                 const float* __restrict__ bias,
                 const int* __restrict__ ctrl,
                 float* __restrict__ out) {
    // expert-clustered XCD swizzle: XCD j owns tiles [20j, 20j+20), nb-fastest
    const int swz = ((int)blockIdx.x & 7) * ((MAX_TILES * 8) >> 3) + ((int)blockIdx.x >> 3);
    const int tileIdx = swz >> 3;
    const int ntiles = ctrl[WS_NTILES];
    if (tileIdx >= ntiles) return;
    const int e     = ctrl[WS_TABLE + tileIdx * 4 + 0];
    const int list0 = ctrl[WS_TABLE + tileIdx * 4 + 1];
    const int nrows = ctrl[WS_TABLE + tileIdx * 4 + 2];
    const int n0 = (swz & 7) * BN;

    __shared__ unsigned short As[BM][BK];   // linear; chunk-swizzled via A-source perm
    __shared__ unsigned short Bs[BN][BK];   // rows = n; chunk phys = o ^ (n&7) ^ ((n>>3)&7)
    __shared__ int rowtok[BM];

    const int t = threadIdx.x;
    const int lane = t & 63, wv = t >> 6;

    if (t < BM) {
        int r = t < nrows ? t : nrows - 1;
        rowtok[t] = ctrl[WS_ROWLIST + list0 + r];
    }
    __syncthreads();

    // A staging (unchanged proven path): source chunk pre-swizzled
    const int cg = (lane & 7) ^ (lane >> 3);
    const unsigned short* asrc[4];
    #pragma unroll
    for (int i = 0; i < 4; ++i) {
        int row = (wv << 5) + (i << 3) + (lane >> 3);
        asrc[i] = xb + (size_t)(rowtok[row] >> 2) * IN_C + (cg << 3);
    }

    // B staging roles: q = n-quad (4 consecutive n), o = k-octet
    const int q = t & 31, o = t >> 5;
    const float* bbase = w + ((size_t)e << 20) + (size_t)(o << 3 << 10) + n0 + (q << 2);

    const int wr = (t >> 7) & 1;          // 2x2 wave grid, 64x64 per wave
    const int wc = (t >> 6) & 1;
    const int lrow = lane & 15, lq = lane >> 4;
    // A fragment byte offsets (kk = 0,1)
    const int afo0 = ((lq) ^ (lrow & 7)) << 4;
    const int afo1 = ((4 + lq) ^ (lrow & 7)) << 4;
    const char* aB = (const char*)&As[wr * 64 + lrow][0];
    const char* bB = (const char*)&Bs[wc * 64 + lrow][0];
    // B fragment offsets depend on nf too: bfo[kk][nf]
    int bfo[2][4];
    #pragma unroll
    for (int kk = 0; kk < 2; ++kk)
        #pragma unroll
        for (int nf = 0; nf < 4; ++nf)
            bfo[kk][nf] = ((((kk << 2) + lq) ^ (lrow & 7) ^ ((2 * nf + (lrow >> 3)) & 7)) << 4);

    f32x4 acc[4][4];
    #pragma unroll
    for (int m = 0; m < 4; ++m)
        #pragma unroll
        for (int n = 0; n < 4; ++n) acc[m][n] = (f32x4)0.f;

    for (int k0 = 0; k0 < IN_C; k0 += BK) {
        __syncthreads();
        // B global loads first (longest latency)
        f32x4 breg[8];
        const float* bsrc = bbase + ((size_t)k0 << 10);
        #pragma unroll
        for (int r = 0; r < 8; ++r)
            breg[r] = *(const f32x4*)(bsrc + ((size_t)r << 10));
        // A direct-to-LDS (stays in flight until barrier)
        #pragma unroll
        for (int i = 0; i < 4; ++i)
            gload16(asrc[i] + k0, &As[(wv << 5) + (i << 3)][0]);
        // B convert + transposed LDS write (waits only the 8 B loads)
        #pragma unroll
        for (int j = 0; j < 4; ++j) {
            const int n = (q << 2) + j;
            const int phys = o ^ (n & 7) ^ ((n >> 3) & 7);
            u16x8 ov;
            #pragma unroll
            for (int r = 0; r < 8; ++r) ov[r] = f2bf(breg[r][j]);
            *(u16x8*)&Bs[n][phys << 3] = ov;
        }
        __syncthreads();

        #pragma unroll
        for (int kk = 0; kk < 2; ++kk) {
            const int afo = kk ? afo1 : afo0;
            bf16x8 a[4], b[4];
            #pragma unroll
            for (int m = 0; m < 4; ++m) a[m] = *(const bf16x8*)(aB + m * 2048 + afo);
            #pragma unroll
            for (int n = 0; n < 4; ++n) b[n] = *(const bf16x8*)(bB + n * 2048 + bfo[kk][n]);
            #pragma unroll
            for (int m = 0; m < 4; ++m)
                #pragma unroll
                for (int n = 0; n < 4; ++n)
                    acc[m][n] = __builtin_amdgcn_mfma_f32_16x16x32_bf16(a[m], b[n], acc[m][n], 0, 0, 0);
        }
    }

    // C/D layout: col = lane&15, row = (lane>>4)*4 + j   [verified m89/m91]
    #pragma unroll
    for (int m = 0; m < 4; ++m) {
        #pragma unroll
        for (int j = 0; j < 4; ++j) {
            int row = wr * 64 + m * 16 + lq * 4 + j;
            if (row < nrows) {
                int s = rowtok[row];
                float* orow = out + (size_t)s * OUT_C;
                #pragma unroll
                for (int n = 0; n < 4; ++n) {
                    int col = n0 + wc * 64 + n * 16 + lrow;
                    float vv = acc[m][n][j] + bias[e * OUT_C + col];
                    orow[col] = vv > 0.f ? vv : 0.f;
                }
            }
        }
    }
}

// ---------------- fallback f32 path (round-1 proven) for small ws ----------------

__global__ void count_kernel(const int* __restrict__ idx, int* __restrict__ ctrl) {
    int s = blockIdx.x * blockDim.x + threadIdx.x;
    if (s < NTOK) atomicAdd(&ctrl[WS_COUNTS + (idx[s] & (N_EXPERTS - 1))], 1);
}

__global__ void scan_kernel(int* __restrict__ ctrl) {
    if (threadIdx.x != 0) return;
    int off = 0, tiles = 0;
    for (int e = 0; e < N_EXPERTS; ++e) {
        int c = ctrl[WS_COUNTS + e];
        ctrl[WS_CURSOR + e] = off;
        for (int t = 0; t < c; t += BM) {
            ctrl[WS_TABLE + tiles * 4 + 0] = e;
            ctrl[WS_TABLE + tiles * 4 + 1] = off + t;
            ctrl[WS_TABLE + tiles * 4 + 2] = (c - t) < BM ? (c - t) : BM;
            ++tiles;
        }
        off += c;
    }
    ctrl[WS_NTILES] = tiles;
}

__global__ void scatter_kernel(const int* __restrict__ idx, int* __restrict__ ctrl) {
    int s = blockIdx.x * blockDim.x + threadIdx.x;
    if (s < NTOK) {
        int e = idx[s] & (N_EXPERTS - 1);
        int p = atomicAdd(&ctrl[WS_CURSOR + e], 1);
        ctrl[WS_ROWLIST + p] = s;
    }
}

__global__ __launch_bounds__(256, 2)
void gemm_f32_kernel(const float* __restrict__ x, const float* __restrict__ w,
                     const float* __restrict__ bias, const int* __restrict__ ctrl,
                     float* __restrict__ out) {
    int ntiles = ctrl[WS_NTILES];
    if ((int)blockIdx.x >= ntiles) return;
    const int e     = ctrl[WS_TABLE + blockIdx.x * 4 + 0];
    const int list0 = ctrl[WS_TABLE + blockIdx.x * 4 + 1];
    const int nrows = ctrl[WS_TABLE + blockIdx.x * 4 + 2];
    const int n0 = blockIdx.y * BN;

    __shared__ unsigned short As2[BM][40];
    __shared__ unsigned short Bs2[BN][40];
    __shared__ int rowtok[BM];

    const int t = threadIdx.x;
    if (t < BM) {
        int r = t < nrows ? t : nrows - 1;
        rowtok[t] = ctrl[WS_ROWLIST + list0 + r];
    }
    __syncthreads();

    const int arow = t >> 1, acol0 = (t & 1) * 16;
    const int brow = t >> 3, bcol0 = (t & 7) * 16;
    const float* xbase = x + (size_t)(rowtok[arow] >> 2) * IN_C + acol0;
    const float* wbase = w + (size_t)e * IN_C * OUT_C + (size_t)brow * OUT_C + n0 + bcol0;

    const int lane = t & 63, wid = t >> 6;
    const int wr = wid >> 1, wc = wid & 1;
    const int lrow = lane & 15, lq = lane >> 4;

    f32x4 acc[4][4];
    #pragma unroll
    for (int m = 0; m < 4; ++m)
        #pragma unroll
        for (int n = 0; n < 4; ++n) acc[m][n] = (f32x4)0.f;

    for (int k0 = 0; k0 < IN_C; k0 += 32) {
        __syncthreads();
        #pragma unroll
        for (int u = 0; u < 4; ++u) {
            f32x4 v = *(const f32x4*)(xbase + k0 + 4 * u);
            ushort4 pk;
            pk.x = f2bf(v[0]); pk.y = f2bf(v[1]); pk.z = f2bf(v[2]); pk.w = f2bf(v[3]);
            *(ushort4*)&As2[arow][acol0 + 4 * u] = pk;
        }
        #pragma unroll
        for (int u = 0; u < 4; ++u) {
            f32x4 v = *(const f32x4*)(wbase + (size_t)k0 * OUT_C + 4 * u);
            Bs2[bcol0 + 4 * u + 0][brow] = f2bf(v[0]);
            Bs2[bcol0 + 4 * u + 1][brow] = f2bf(v[1]);
            Bs2[bcol0 + 4 * u + 2][brow] = f2bf(v[2]);
            Bs2[bcol0 + 4 * u + 3][brow] = f2bf(v[3]);
        }
        __syncthreads();

        bf16x8 a[4], b[4];
        #pragma unroll
        for (int m = 0; m < 4; ++m) a[m] = *(const bf16x8*)&As2[wr * 64 + m * 16 + lrow][lq * 8];
        #pragma unroll
        for (int n = 0; n < 4; ++n) b[n] = *(const bf16x8*)&Bs2[wc * 64 + n * 16 + lrow][lq * 8];
        #pragma unroll
        for (int m = 0; m < 4; ++m)
            #pragma unroll
            for (int n = 0; n < 4; ++n)
                acc[m][n] = __builtin_amdgcn_mfma_f32_16x16x32_bf16(a[m], b[n], acc[m][n], 0, 0, 0);
    }

    #pragma unroll
    for (int m = 0; m < 4; ++m) {
        #pragma unroll
        for (int j = 0; j < 4; ++j) {
            int row = wr * 64 + m * 16 + lq * 4 + j;
            if (row < nrows) {
                int s = rowtok[row];
                float* orow = out + (size_t)s * OUT_C;
                #pragma unroll
                for (int n = 0; n < 4; ++n) {
                    int col = n0 + wc * 64 + n * 16 + lrow;
                    float vv = acc[m][n][j] + bias[e * OUT_C + col];
                    orow[col] = vv > 0.f ? vv : 0.f;
                }
            }
        }
    }
}

// ---------------- launch ----------------

extern "C" void kernel_launch(void* const* d_in, const int* in_sizes, int n_in,
                              void* d_out, int out_size, void* d_ws, size_t ws_size,
                              hipStream_t stream) {
    const float* x    = (const float*)d_in[0];
    const int*   idx  = (const int*)d_in[1];
    const float* w    = (const float*)d_in[2];
    const float* bias = (const float*)d_in[3];
    float* out = (float*)d_out;

    const size_t need = CTRL_OFF_BYTES + (size_t)(CTRL_INTS + 64) * sizeof(int);
    if (ws_size >= need) {
        unsigned short* xb = (unsigned short*)d_ws;
        int* ctrl = (int*)((char*)d_ws + CTRL_OFF_BYTES);

        prep_kernel<<<PREP_NWG, 256, 0, stream>>>(x, idx, xb, ctrl);
        gemm_kernel<<<MAX_TILES * 8, 256, 0, stream>>>(xb, w, bias, ctrl, out);
    } else {
        int* ctrl = (int*)d_ws;
        hipMemsetAsync(ctrl, 0, (CTRL_INTS + 64) * sizeof(int), stream);
        count_kernel<<<NTOK / 256, 256, 0, stream>>>(idx, ctrl);
        scan_kernel<<<1, 64, 0, stream>>>(ctrl);
        scatter_kernel<<<NTOK / 256, 256, 0, stream>>>(idx, ctrl);
        dim3 grid(MAX_TILES, OUT_C / BN);
        gemm_f32_kernel<<<grid, 256, 0, stream>>>(x, w, bias, ctrl, out);
    }
}

// Round 7
// 104.797 us; speedup vs baseline: 1.2959x; 1.0050x over previous
//
#include <hip/hip_runtime.h>
#include <hip/hip_bf16.h>

#define N_EXPERTS 32
#define K_SEL 4
#define IN_C 1024
#define OUT_C 1024
#define BATCH 4096
#define NTOK (BATCH * K_SEL)   // 16384

#define BM 128
#define BN 128
#define BK 64
#define MAX_TILES (N_EXPERTS + NTOK / BM)   // 160 worst case

// workspace layout: xb (bf16) then ctrl ints
#define XB_ELEMS (BATCH * IN_C)                      // 4,194,304
#define CTRL_OFF_BYTES ((size_t)XB_ELEMS * 2)

#define WS_NTILES 0
#define WS_TABLE 8                          // 4 ints per tile
#define WS_ROWLIST (WS_TABLE + MAX_TILES * 4)
#define CTRL_INTS (WS_ROWLIST + NTOK)
// fallback layout additions
#define WS_COUNTS (CTRL_INTS)
#define WS_CURSOR (CTRL_INTS + 32)

typedef __attribute__((ext_vector_type(4))) float f32x4;
typedef __attribute__((ext_vector_type(8))) short bf16x8;
typedef __attribute__((ext_vector_type(8))) unsigned short u16x8;

__device__ __forceinline__ unsigned short f2bf(float f) {
    union { float f; unsigned u; } v; v.f = f;
    unsigned r = v.u + 0x7fffu + ((v.u >> 16) & 1u);   // RNE
    return (unsigned short)(r >> 16);
}

__device__ __forceinline__ void gload16(const void* g, void* l) {
    __builtin_amdgcn_global_load_lds(
        (const __attribute__((address_space(1))) unsigned int*)g,
        (__attribute__((address_space(3))) unsigned int*)l, 16, 0, 0);
}

// ---------------- prep: bucket (bid 0) + xconv ----------------

#define XCONV_B0 1
#define XCONV_NB (XB_ELEMS / 2048)          // 2048
#define PREP_NWG (XCONV_B0 + XCONV_NB)      // 2049

__global__ __launch_bounds__(256)
void prep_kernel(const float* __restrict__ x, const int* __restrict__ idx,
                 unsigned short* __restrict__ xb, int* __restrict__ ctrl) {
    const int bid = blockIdx.x;
    const int t = threadIdx.x;

    if (bid >= XCONV_B0) {
        // ---- x f32 -> bf16 ----
        int i = ((bid - XCONV_B0) * 256 + t) << 3;
        f32x4 v0 = *(const f32x4*)(x + i);
        f32x4 v1 = *(const f32x4*)(x + i + 4);
        u16x8 o;
        o[0] = f2bf(v0[0]); o[1] = f2bf(v0[1]); o[2] = f2bf(v0[2]); o[3] = f2bf(v0[3]);
        o[4] = f2bf(v1[0]); o[5] = f2bf(v1[1]); o[6] = f2bf(v1[2]); o[7] = f2bf(v1[3]);
        *(u16x8*)(xb + i) = o;
    } else {
        // ---- bucketing: count -> scan -> table -> scatter, one block ----
        __shared__ int cnt[N_EXPERTS], base[N_EXPERTS], tbase[N_EXPERTS];
        if (t < N_EXPERTS) cnt[t] = 0;
        __syncthreads();
        #pragma unroll 4
        for (int i = 0; i < NTOK / 256; ++i) {
            int e = idx[i * 256 + t] & (N_EXPERTS - 1);
            atomicAdd(&cnt[e], 1);
        }
        __syncthreads();
        if (t == 0) {
            int off = 0, tiles = 0;
            for (int e = 0; e < N_EXPERTS; ++e) {
                base[e] = off;
                tbase[e] = tiles;
                int c = cnt[e];
                tiles += (c + BM - 1) / BM;
                off += c;
            }
            ctrl[WS_NTILES] = tiles;
        }
        __syncthreads();
        if (t < N_EXPERTS) {
            int c = cnt[t], off = base[t], tt = tbase[t];
            for (int u = 0; u < c; u += BM, ++tt) {
                ctrl[WS_TABLE + tt * 4 + 0] = t;
                ctrl[WS_TABLE + tt * 4 + 1] = off + u;
                ctrl[WS_TABLE + tt * 4 + 2] = (c - u) < BM ? (c - u) : BM;
            }
            cnt[t] = off;   // becomes scatter cursor
        }
        __syncthreads();
        #pragma unroll 4
        for (int i = 0; i < NTOK / 256; ++i) {
            int s = i * 256 + t;
            int e = idx[s] & (N_EXPERTS - 1);
            int p = atomicAdd(&cnt[e], 1);
            ctrl[WS_ROWLIST + p] = s;
        }
    }
}

// -------- fused bf16 grouped GEMM, software-pipelined B (counted vmcnt) --------

__global__ __launch_bounds__(256, 3)
void gemm_kernel(const unsigned short* __restrict__ xb,
                 const float* __restrict__ w,
                 const float* __restrict__ bias,
                 const int* __restrict__ ctrl,
                 float* __restrict__ out) {
    // expert-clustered XCD swizzle: XCD j owns tiles [20j, 20j+20), nb-fastest
    const int swz = ((int)blockIdx.x & 7) * ((MAX_TILES * 8) >> 3) + ((int)blockIdx.x >> 3);
    const int tileIdx = swz >> 3;
    const int ntiles = ctrl[WS_NTILES];
    if (tileIdx >= ntiles) return;
    const int e     = ctrl[WS_TABLE + tileIdx * 4 + 0];
    const int list0 = ctrl[WS_TABLE + tileIdx * 4 + 1];
    const int nrows = ctrl[WS_TABLE + tileIdx * 4 + 2];
    const int n0 = (swz & 7) * BN;

    __shared__ unsigned short As[BM][BK];   // linear; chunk-swizzled via A-source perm
    __shared__ unsigned short Bs[BN][BK];   // rows = n; chunk phys = o ^ (n&7) ^ ((n>>3)&7)
    __shared__ int rowtok[BM];

    const int t = threadIdx.x;
    const int lane = t & 63, wv = t >> 6;

    if (t < BM) {
        int r = t < nrows ? t : nrows - 1;
        rowtok[t] = ctrl[WS_ROWLIST + list0 + r];
    }
    __syncthreads();

    // A staging (proven path): source chunk pre-swizzled
    const int cg = (lane & 7) ^ (lane >> 3);
    const unsigned short* asrc[4];
    #pragma unroll
    for (int i = 0; i < 4; ++i) {
        int row = (wv << 5) + (i << 3) + (lane >> 3);
        asrc[i] = xb + (size_t)(rowtok[row] >> 2) * IN_C + (cg << 3);
    }

    // B staging roles: q = n-quad (4 consecutive n), o = k-octet
    const int q = t & 31, o = t >> 5;
    const float* bbase = w + ((size_t)e << 20) + (size_t)(o << 3 << 10) + n0 + (q << 2);

    const int wr = (t >> 7) & 1;          // 2x2 wave grid, 64x64 per wave
    const int wc = (t >> 6) & 1;
    const int lrow = lane & 15, lq = lane >> 4;
    const int afo0 = ((lq) ^ (lrow & 7)) << 4;
    const int afo1 = ((4 + lq) ^ (lrow & 7)) << 4;
    const char* aB = (const char*)&As[wr * 64 + lrow][0];
    const char* bB = (const char*)&Bs[wc * 64 + lrow][0];
    int bfo[2][4];
    #pragma unroll
    for (int kk = 0; kk < 2; ++kk)
        #pragma unroll
        for (int nf = 0; nf < 4; ++nf)
            bfo[kk][nf] = ((((kk << 2) + lq) ^ (lrow & 7) ^ ((2 * nf + (lrow >> 3)) & 7)) << 4);

    f32x4 acc[4][4];
    #pragma unroll
    for (int m = 0; m < 4; ++m)
        #pragma unroll
        for (int n = 0; n < 4; ++n) acc[m][n] = (f32x4)0.f;

    // prologue: B(k=0) loads in flight
    f32x4 breg[8];
    #pragma unroll
    for (int r = 0; r < 8; ++r)
        breg[r] = *(const f32x4*)(bbase + ((size_t)r << 10));

    for (int k0 = 0; k0 < IN_C; k0 += BK) {
        // barrier #1: all waves finished LDS reads of prior step
        asm volatile("s_waitcnt lgkmcnt(0)" ::: "memory");
        __builtin_amdgcn_s_barrier();
        // A direct-to-LDS (4 VMEM ops; stay in flight past the convert)
        #pragma unroll
        for (int i = 0; i < 4; ++i)
            gload16(asrc[i] + k0, &As[(wv << 5) + (i << 3)][0]);
        __builtin_amdgcn_sched_barrier(0);
        // convert B(k) -> Bs (compiler auto-waits vmcnt(4): breg done, A in flight)
        #pragma unroll
        for (int j = 0; j < 4; ++j) {
            const int n = (q << 2) + j;
            const int phys = o ^ (n & 7) ^ ((n >> 3) & 7);
            u16x8 ov;
            #pragma unroll
            for (int r = 0; r < 8; ++r) ov[r] = f2bf(breg[r][j]);
            *(u16x8*)&Bs[n][phys << 3] = ov;
        }
        __builtin_amdgcn_sched_barrier(0);
        // prefetch B(k+1) (wrap on last iter: harmless in-bounds re-read)
        {
            const int kn = (k0 + BK < IN_C) ? (k0 + BK) : 0;
            const float* bs2 = bbase + ((size_t)kn << 10);
            #pragma unroll
            for (int r = 0; r < 8; ++r)
                breg[r] = *(const f32x4*)(bs2 + ((size_t)r << 10));
        }
        __builtin_amdgcn_sched_barrier(0);
        // A's 4 gload_lds done; 8 B prefetch loads REMAIN IN FLIGHT across barrier
        asm volatile("s_waitcnt vmcnt(8)" ::: "memory");
        asm volatile("s_waitcnt lgkmcnt(0)" ::: "memory");
        __builtin_amdgcn_sched_barrier(0);
        __builtin_amdgcn_s_barrier();      // barrier #2: tile ready
        #pragma unroll
        for (int kk = 0; kk < 2; ++kk) {
            const int afo = kk ? afo1 : afo0;
            bf16x8 a[4], b[4];
            #pragma unroll
            for (int m = 0; m < 4; ++m) a[m] = *(const bf16x8*)(aB + m * 2048 + afo);
            #pragma unroll
            for (int n = 0; n < 4; ++n) b[n] = *(const bf16x8*)(bB + n * 2048 + bfo[kk][n]);
            #pragma unroll
            for (int m = 0; m < 4; ++m)
                #pragma unroll
                for (int n = 0; n < 4; ++n)
                    acc[m][n] = __builtin_amdgcn_mfma_f32_16x16x32_bf16(a[m], b[n], acc[m][n], 0, 0, 0);
        }
    }

    // C/D layout: col = lane&15, row = (lane>>4)*4 + j   [verified m89/m91]
    #pragma unroll
    for (int m = 0; m < 4; ++m) {
        #pragma unroll
        for (int j = 0; j < 4; ++j) {
            int row = wr * 64 + m * 16 + lq * 4 + j;
            if (row < nrows) {
                int s = rowtok[row];
                float* orow = out + (size_t)s * OUT_C;
                #pragma unroll
                for (int n = 0; n < 4; ++n) {
                    int col = n0 + wc * 64 + n * 16 + lrow;
                    float vv = acc[m][n][j] + bias[e * OUT_C + col];
                    orow[col] = vv > 0.f ? vv : 0.f;
                }
            }
        }
    }
}

// ---------------- fallback f32 path (round-1 proven) for small ws ----------------

__global__ void count_kernel(const int* __restrict__ idx, int* __restrict__ ctrl) {
    int s = blockIdx.x * blockDim.x + threadIdx.x;
    if (s < NTOK) atomicAdd(&ctrl[WS_COUNTS + (idx[s] & (N_EXPERTS - 1))], 1);
}

__global__ void scan_kernel(int* __restrict__ ctrl) {
    if (threadIdx.x != 0) return;
    int off = 0, tiles = 0;
    for (int e = 0; e < N_EXPERTS; ++e) {
        int c = ctrl[WS_COUNTS + e];
        ctrl[WS_CURSOR + e] = off;
        for (int t = 0; t < c; t += BM) {
            ctrl[WS_TABLE + tiles * 4 + 0] = e;
            ctrl[WS_TABLE + tiles * 4 + 1] = off + t;
            ctrl[WS_TABLE + tiles * 4 + 2] = (c - t) < BM ? (c - t) : BM;
            ++tiles;
        }
        off += c;
    }
    ctrl[WS_NTILES] = tiles;
}

__global__ void scatter_kernel(const int* __restrict__ idx, int* __restrict__ ctrl) {
    int s = blockIdx.x * blockDim.x + threadIdx.x;
    if (s < NTOK) {
        int e = idx[s] & (N_EXPERTS - 1);
        int p = atomicAdd(&ctrl[WS_CURSOR + e], 1);
        ctrl[WS_ROWLIST + p] = s;
    }
}

__global__ __launch_bounds__(256, 2)
void gemm_f32_kernel(const float* __restrict__ x, const float* __restrict__ w,
                     const float* __restrict__ bias, const int* __restrict__ ctrl,
                     float* __restrict__ out) {
    int ntiles = ctrl[WS_NTILES];
    if ((int)blockIdx.x >= ntiles) return;
    const int e     = ctrl[WS_TABLE + blockIdx.x * 4 + 0];
    const int list0 = ctrl[WS_TABLE + blockIdx.x * 4 + 1];
    const int nrows = ctrl[WS_TABLE + blockIdx.x * 4 + 2];
    const int n0 = blockIdx.y * BN;

    __shared__ unsigned short As2[BM][40];
    __shared__ unsigned short Bs2[BN][40];
    __shared__ int rowtok[BM];

    const int t = threadIdx.x;
    if (t < BM) {
        int r = t < nrows ? t : nrows - 1;
        rowtok[t] = ctrl[WS_ROWLIST + list0 + r];
    }
    __syncthreads();

    const int arow = t >> 1, acol0 = (t & 1) * 16;
    const int brow = t >> 3, bcol0 = (t & 7) * 16;
    const float* xbase = x + (size_t)(rowtok[arow] >> 2) * IN_C + acol0;
    const float* wbase = w + (size_t)e * IN_C * OUT_C + (size_t)brow * OUT_C + n0 + bcol0;

    const int lane = t & 63, wid = t >> 6;
    const int wr = wid >> 1, wc = wid & 1;
    const int lrow = lane & 15, lq = lane >> 4;

    f32x4 acc[4][4];
    #pragma unroll
    for (int m = 0; m < 4; ++m)
        #pragma unroll
        for (int n = 0; n < 4; ++n) acc[m][n] = (f32x4)0.f;

    for (int k0 = 0; k0 < IN_C; k0 += 32) {
        __syncthreads();
        #pragma unroll
        for (int u = 0; u < 4; ++u) {
            f32x4 v = *(const f32x4*)(xbase + k0 + 4 * u);
            ushort4 pk;
            pk.x = f2bf(v[0]); pk.y = f2bf(v[1]); pk.z = f2bf(v[2]); pk.w = f2bf(v[3]);
            *(ushort4*)&As2[arow][acol0 + 4 * u] = pk;
        }
        #pragma unroll
        for (int u = 0; u < 4; ++u) {
            f32x4 v = *(const f32x4*)(wbase + (size_t)k0 * OUT_C + 4 * u);
            Bs2[bcol0 + 4 * u + 0][brow] = f2bf(v[0]);
            Bs2[bcol0 + 4 * u + 1][brow] = f2bf(v[1]);
            Bs2[bcol0 + 4 * u + 2][brow] = f2bf(v[2]);
            Bs2[bcol0 + 4 * u + 3][brow] = f2bf(v[3]);
        }
        __syncthreads();

        bf16x8 a[4], b[4];
        #pragma unroll
        for (int m = 0; m < 4; ++m) a[m] = *(const bf16x8*)&As2[wr * 64 + m * 16 + lrow][lq * 8];
        #pragma unroll
        for (int n = 0; n < 4; ++n) b[n] = *(const bf16x8*)&Bs2[wc * 64 + n * 16 + lrow][lq * 8];
        #pragma unroll
        for (int m = 0; m < 4; ++m)
            #pragma unroll
            for (int n = 0; n < 4; ++n)
                acc[m][n] = __builtin_amdgcn_mfma_f32_16x16x32_bf16(a[m], b[n], acc[m][n], 0, 0, 0);
    }

    #pragma unroll
    for (int m = 0; m < 4; ++m) {
        #pragma unroll
        for (int j = 0; j < 4; ++j) {
            int row = wr * 64 + m * 16 + lq * 4 + j;
            if (row < nrows) {
                int s = rowtok[row];
                float* orow = out + (size_t)s * OUT_C;
                #pragma unroll
                for (int n = 0; n < 4; ++n) {
                    int col = n0 + wc * 64 + n * 16 + lrow;
                    float vv = acc[m][n][j] + bias[e * OUT_C + col];
                    orow[col] = vv > 0.f ? vv : 0.f;
                }
            }
        }
    }
}

// ---------------- launch ----------------

extern "C" void kernel_launch(void* const* d_in, const int* in_sizes, int n_in,
                              void* d_out, int out_size, void* d_ws, size_t ws_size,
                              hipStream_t stream) {
    const float* x    = (const float*)d_in[0];
    const int*   idx  = (const int*)d_in[1];
    const float* w    = (const float*)d_in[2];
    const float* bias = (const float*)d_in[3];
    float* out = (float*)d_out;

    const size_t need = CTRL_OFF_BYTES + (size_t)(CTRL_INTS + 64) * sizeof(int);
    if (ws_size >= need) {
        unsigned short* xb = (unsigned short*)d_ws;
        int* ctrl = (int*)((char*)d_ws + CTRL_OFF_BYTES);

        prep_kernel<<<PREP_NWG, 256, 0, stream>>>(x, idx, xb, ctrl);
        gemm_kernel<<<MAX_TILES * 8, 256, 0, stream>>>(xb, w, bias, ctrl, out);
    } else {
        int* ctrl = (int*)d_ws;
        hipMemsetAsync(ctrl, 0, (CTRL_INTS + 64) * sizeof(int), stream);
        count_kernel<<<NTOK / 256, 256, 0, stream>>>(idx, ctrl);
        scan_kernel<<<1, 64, 0, stream>>>(ctrl);
        scatter_kernel<<<NTOK / 256, 256, 0, stream>>>(idx, ctrl);
        dim3 grid(MAX_TILES, OUT_C / BN);
        gemm_f32_kernel<<<grid, 256, 0, stream>>>(x, w, bias, ctrl, out);
    }
}